// Round 4
// baseline (282.004 us; speedup 1.0000x reference)
//
#include <hip/hip_runtime.h>

// Problem constants
#define LSEQ 512      // L
#define DDIM 256      // D
#define PDIM 128      // PAIR_DIM
#define BLROWS 1024   // B * L
#define ROWS 4        // h-rows per block in projection kernel
#define ITILE 8       // i rows per bcast block
#define JTILE 64      // j cols per bcast block

// clang native vector type for nontemporal stores (HIP float4 is a struct,
// which __builtin_nontemporal_store rejects).
typedef float nt_f4 __attribute__((ext_vector_type(4)));

// Kernel 1: P1[bl][p]  = dot(h[bl,:], W[p, 0:256])
//           P2b[bl][p] = dot(h[bl,:], W[p, 256:512]) + bias[p]
// 256 blocks x 256 threads; threads 0..127 -> P1, 128..255 -> P2b.
__global__ __launch_bounds__(256) void pair_proj(
    const float* __restrict__ h, const float* __restrict__ W,
    const float* __restrict__ bias, float* __restrict__ P1,
    float* __restrict__ P2b)
{
    __shared__ float4 hsh[ROWS * (DDIM / 4)];  // 4 rows x 64 float4 = 4 KB

    const int t   = threadIdx.x;
    const int bl0 = blockIdx.x * ROWS;

    const float4* h4 = (const float4*)h + (size_t)bl0 * (DDIM / 4);
    hsh[t] = h4[t];
    __syncthreads();

    const int p    = t & (PDIM - 1);
    const int half = t >> 7;  // 0 -> W1 (P1), 1 -> W2 (P2b)

    const float4* w4 = (const float4*)(W + (size_t)p * (2 * DDIM) + half * DDIM);

    float acc[ROWS];
#pragma unroll
    for (int r = 0; r < ROWS; ++r) acc[r] = 0.f;

#pragma unroll 8
    for (int d4 = 0; d4 < DDIM / 4; ++d4) {
        const float4 w = w4[d4];
#pragma unroll
        for (int r = 0; r < ROWS; ++r) {
            const float4 hh = hsh[r * (DDIM / 4) + d4];  // wave-uniform -> LDS broadcast
            acc[r] = fmaf(w.x, hh.x, acc[r]);
            acc[r] = fmaf(w.y, hh.y, acc[r]);
            acc[r] = fmaf(w.z, hh.z, acc[r]);
            acc[r] = fmaf(w.w, hh.w, acc[r]);
        }
    }

    float* dst     = half ? P2b : P1;
    const float bb = half ? bias[p] : 0.f;
#pragma unroll
    for (int r = 0; r < ROWS; ++r)
        dst[(size_t)(bl0 + r) * PDIM + p] = acc[r] + bb;
}

// Kernel 2: out[b,i,j,p] = P1[b,i,p] + P2b[b,j,p]
// grid (128, 8): block = 8 consecutive i (one b; 512%8==0 so tiles don't
// straddle b) x 64 consecutive j. Each P2b read is reused across 8 i rows,
// cutting logical read traffic 8x (cache-independent). Per-thread: 16 loads,
// 64 NT stores; per-wave store burst = 1 KB contiguous.
__global__ __launch_bounds__(256) void bcast_add(
    const float4* __restrict__ P1, const float4* __restrict__ P2b,
    nt_f4* __restrict__ out)
{
    const int t  = threadIdx.x;
    const int p4 = t & 31;               // float4 index along p (0..31)
    const int jl = t >> 5;               // 0..7
    const int i0 = blockIdx.x * ITILE;   // base bi = b*512 + i
    const int b  = i0 >> 9;
    const int j0 = blockIdx.y * JTILE + jl;

    // 8 P2b vectors: j = j0 + 8k, k=0..7
    float4 v[8];
    const float4* src = P2b + ((size_t)(b * LSEQ + j0)) * 32 + p4;
#pragma unroll
    for (int k = 0; k < 8; ++k)
        v[k] = src[(size_t)k * 8 * 32];

    // 8 P1 vectors: i0..i0+7
    float4 a[ITILE];
#pragma unroll
    for (int r = 0; r < ITILE; ++r)
        a[r] = P1[(size_t)(i0 + r) * 32 + p4];

#pragma unroll
    for (int r = 0; r < ITILE; ++r) {
        nt_f4* dst = out + ((size_t)(i0 + r) * LSEQ + j0) * 32 + p4;
#pragma unroll
        for (int k = 0; k < 8; ++k) {
            nt_f4 o;
            o.x = v[k].x + a[r].x;
            o.y = v[k].y + a[r].y;
            o.z = v[k].z + a[r].z;
            o.w = v[k].w + a[r].w;
            __builtin_nontemporal_store(o, &dst[(size_t)k * 256]);
        }
    }
}

extern "C" void kernel_launch(void* const* d_in, const int* in_sizes, int n_in,
                              void* d_out, int out_size, void* d_ws, size_t ws_size,
                              hipStream_t stream) {
    const float* h    = (const float*)d_in[0];  // (2, 512, 256) fp32
    const float* W    = (const float*)d_in[1];  // (128, 512)    fp32
    const float* bias = (const float*)d_in[2];  // (128,)        fp32

    float* P1  = (float*)d_ws;                  // 1024 x 128 fp32 = 512 KB
    float* P2b = P1 + (size_t)BLROWS * PDIM;    // 1024 x 128 fp32 = 512 KB

    pair_proj<<<dim3(BLROWS / ROWS), dim3(256), 0, stream>>>(h, W, bias, P1, P2b);

    dim3 g2(BLROWS / ITILE, LSEQ / JTILE);
    bcast_add<<<g2, dim3(256), 0, stream>>>((const float4*)P1, (const float4*)P2b,
                                            (nt_f4*)d_out);
}